// Round 4
// baseline (363.282 us; speedup 1.0000x reference)
//
#include <hip/hip_runtime.h>
#include <hip/hip_bf16.h>

// FastUpConvolution on MI355X — round 4: all-f32 I/O (reference dtypes).
// The 4 convs (3x3, 2x3, 3x2, 2x2 with matching pads) are one implicit GEMM
//   C[nout=4*256][m=16*32*32] = W[nout][K=9*512] * X[m][K]^T
// over NHWC-padded x with zero-padded taps. Compute in bf16 MFMA (inputs
// converted once in prep; error ~0.003 per element pre-BN vs 0.12 threshold).
// Pipeline: prep_x (f32 NCHW -> bf16 NHWC pad) -> prep_w -> gemm (MFMA,
// f32 pre-BN y into d_out, pixel-shuffled) -> bn_stats -> bn_apply.
//
// Rounds 1-3 post-mortem: inputs/outputs are FLOAT32 per the reference;
// misreading f32 as bf16 made BN stats Inf/NaN -> relu(NaN)=0 -> all-zero
// output -> absmax == max|ref| == 6.0 exactly (R1/R2); R3 fixed the inputs
// but wrote bf16 into the f32 output buffer (half-filled -> same signature).
//
// ws layout (28.4 MiB):
//   x_t   : bf16 [16][34][34][512]  @ 0          (18,939,904 B)
//   W_t   : bf16 [1024][9*512]      @ 18,939,904 ( 9,437,184 B)
//   bias  : f32  [1024]             @ 28,377,088 (     4,096 B)
//   stats : f32  [512] mean|rstd    @ 28,381,184 (     2,048 B)

typedef unsigned short ushort_t;
typedef __attribute__((ext_vector_type(8))) short short8;
typedef __attribute__((ext_vector_type(4))) float floatx4;
typedef __attribute__((ext_vector_type(4))) unsigned short u16x4;
typedef __attribute__((ext_vector_type(8))) unsigned short u16x8;
typedef __attribute__((ext_vector_type(4))) unsigned int u32x4;

#define XT_OFF    0u
#define WT_OFF    18939904u
#define BIAS_OFF  28377088u
#define STATS_OFF 28381184u

// LDS row stride for the GEMM tiles: 64 bf16 = 128 B data + 16 B pad.
#define LROW 144

__device__ __forceinline__ ushort_t f2bf(float f) {
  unsigned int u = __builtin_bit_cast(unsigned int, f);
  u += 0x7fffu + ((u >> 16) & 1u);   // RNE (values are finite here)
  return (ushort_t)(u >> 16);
}

// ---------------------------------------------------------------- prep_x ---
// x[16][512][32][32] (f32) -> x_t[16][34][34][512] bf16, zero-padded NHWC.
// One block per (n, hp). LDS transpose, 128 ci x 32 w per pass.
__global__ __launch_bounds__(256) void prep_x(const float* __restrict__ x,
                                              ushort_t* __restrict__ xt) {
  const int b = blockIdx.x;
  const int n = b / 34, hp = b % 34;
  const int t = threadIdx.x;
  ushort_t* dst = xt + (size_t)(n * 34 + hp) * (34 * 512);
  if (hp == 0 || hp == 33) {              // top/bottom pad rows: zero slice
    u32x4 z = {0u, 0u, 0u, 0u};
    for (int i = t; i < 2176; i += 256) ((u32x4*)dst)[i] = z;
    return;
  }
  const int h = hp - 1;
  {                                        // left/right pad columns
    u32x4 z = {0u, 0u, 0u, 0u};
    if (t < 64) ((u32x4*)dst)[t] = z;
    else if (t < 128) ((u32x4*)(dst + 33 * 512))[t - 64] = z;
  }
  __shared__ ushort_t lds[128 * 36];       // stride 36: 8B align, non-2^k
  const size_t base = (size_t)n * 524288 + (size_t)h * 32;
  for (int ci0 = 0; ci0 < 512; ci0 += 128) {
    __syncthreads();
    {  // load: coalesced along w (f32x4 -> bf16x4)
      const int cil = t >> 3;
      const int w4 = (t & 7) << 2;
#pragma unroll
      for (int cc = 0; cc < 4; ++cc) {
        const int ci = cil + cc * 32;
        floatx4 v = *(const floatx4*)(x + base + (size_t)(ci0 + ci) * 1024 + w4);
        u16x4 hv;
#pragma unroll
        for (int j = 0; j < 4; ++j) hv[j] = f2bf(v[j]);
        *(u16x4*)&lds[ci * 36 + w4] = hv;
      }
    }
    __syncthreads();
    {  // store: 16B contiguous along ci
      const int w = t & 31;
      const int j8 = t >> 5;
#pragma unroll
      for (int cc2 = 0; cc2 < 2; ++cc2) {
        const int cil = cc2 * 64 + j8 * 8;
        u16x8 v;
#pragma unroll
        for (int j = 0; j < 8; ++j) v[j] = lds[(cil + j) * 36 + w];
        *(u16x8*)(dst + (w + 1) * 512 + ci0 + cil) = v;
      }
    }
  }
}

// ---------------------------------------------------------------- prep_w ---
// W_t[nout][tap][ci] bf16, nout = q*256+co, tap = dh*3+dw; absent taps -> 0.
// q0=o1(3x3) q1=o2(2x3) q2=o3(3x2) q3=o4(2x2). Also bias[nout] (f32).
__global__ __launch_bounds__(256) void prep_w(
    const float* __restrict__ w1, const float* __restrict__ w2,
    const float* __restrict__ w3, const float* __restrict__ w4,
    const float* __restrict__ b1, const float* __restrict__ b2,
    const float* __restrict__ b3, const float* __restrict__ b4,
    ushort_t* __restrict__ wt, float* __restrict__ bias) {
  const int nout = blockIdx.x;
  const int q = nout >> 8, co = nout & 255;
  const int t = threadIdx.x;
  const float* wsrc; const float* bsrc; int khl, kwl;
  if (q == 0)      { wsrc = w1; bsrc = b1; khl = 3; kwl = 3; }
  else if (q == 1) { wsrc = w2; bsrc = b2; khl = 2; kwl = 3; }
  else if (q == 2) { wsrc = w3; bsrc = b3; khl = 3; kwl = 2; }
  else             { wsrc = w4; bsrc = b4; khl = 2; kwl = 2; }
  if (t == 0) bias[nout] = bsrc[co];
  ushort_t* dst = wt + (size_t)nout * 4608;
  for (int tap = 0; tap < 9; ++tap) {
    const int dh = tap / 3, dw = tap % 3;
    const bool valid = (dh < khl) && (dw < kwl);
#pragma unroll
    for (int cc = 0; cc < 2; ++cc) {
      const int ci = cc * 256 + t;
      ushort_t v = 0;
      if (valid) v = f2bf(wsrc[(((size_t)co * 512 + ci) * khl + dh) * kwl + dw]);
      dst[tap * 512 + ci] = v;
    }
  }
}

// ------------------------------------------------------------------ gemm ---
// 128(nout) x 128(m) tile, 4 waves, each 4x4 frags of mfma_f32_16x16x32_bf16.
// BK=64 (2 k-steps per LDS fill). Staging: u32x4 global loads -> regs ->
// ds_write_b128 into padded rows (LROW=144 B breaks the 2^k bank stride).
// Epilogue: +bias, f32 pixel-shuffle scatter into d_out.
__global__ __launch_bounds__(256) void gemm_kernel(
    const ushort_t* __restrict__ xt, const ushort_t* __restrict__ wt,
    const float* __restrict__ bias, float* __restrict__ out) {
  __shared__ char ldsX[128 * LROW];
  __shared__ char ldsW[128 * LROW];
  const int tid = threadIdx.x;
  const int bx = blockIdx.x;
  const int bn = bx & 7, bm = bx >> 3;
  const int m0 = bm << 7, n0 = bn << 7;
  const int n_img = m0 >> 10;          // block never crosses an image
  const int h0 = (m0 >> 5) & 31;       // block spans h0..h0+3, all w
  const int wv = tid >> 6, lane = tid & 63;

  // staging: thread -> (row8 = tid>>3 in [0,32), 16B chunk = tid&7);
  // handles rows {i*32 + row8 : i in 0..3} for both tiles.
  const int row8 = tid >> 3;
  const int ckb = (tid & 7) << 4;

  const char* xb[4];
  const char* wb[4];
#pragma unroll
  for (int i = 0; i < 4; ++i) {
    xb[i] = (const char*)xt + (((n_img * 34 + h0 + i) * 34 + row8) << 10) + ckb;
    wb[i] = (const char*)wt + (size_t)(n0 + i * 32 + row8) * 9216 + ckb;
  }
  char* lXw = ldsX + row8 * LROW + ckb;
  char* lWw = ldsW + row8 * LROW + ckb;

  floatx4 acc[4][4] = {};

  const int wm = (wv & 1) << 6;        // m-quadrant of this wave
  const int wn = (wv >> 1) << 6;       // nout-quadrant of this wave
  const int ri = lane & 15, kg = lane >> 4;

  int dh = 0, dw = 0;
  for (int tap = 0; tap < 9; ++tap) {
    const int toff = (dh * 34 + dw) << 10;   // byte offset into x_t per tap
    const int wk0 = tap << 10;               // byte offset into W_t row
    for (int c8 = 0; c8 < 8; ++c8) {
      const int cb = c8 << 7;                // 128 B of K per fill
      u32x4 xv[4], wv4[4];
#pragma unroll
      for (int i = 0; i < 4; ++i) {
        xv[i] = *(const u32x4*)(xb[i] + toff + cb);
        wv4[i] = *(const u32x4*)(wb[i] + wk0 + cb);
      }
      __syncthreads();                       // prior reads of LDS done
#pragma unroll
      for (int i = 0; i < 4; ++i) {
        *(u32x4*)(lXw + i * 32 * LROW) = xv[i];
        *(u32x4*)(lWw + i * 32 * LROW) = wv4[i];
      }
      __syncthreads();                       // writes visible
#pragma unroll
      for (int ks = 0; ks < 2; ++ks) {
        const int cl = (ks << 2) + kg;       // 16B chunk index in row
        short8 a4[4], b4v[4];
#pragma unroll
        for (int f = 0; f < 4; ++f) {
          const int rA = wn + (f << 4) + ri;
          a4[f]  = *(const short8*)(ldsW + rA * LROW + (cl << 4));
          const int rB = wm + (f << 4) + ri;
          b4v[f] = *(const short8*)(ldsX + rB * LROW + (cl << 4));
        }
#pragma unroll
        for (int fi = 0; fi < 4; ++fi)
#pragma unroll
          for (int fj = 0; fj < 4; ++fj)
            acc[fi][fj] = __builtin_amdgcn_mfma_f32_16x16x32_bf16(
                a4[fi], b4v[fj], acc[fi][fj], 0, 0, 0);
      }
    }
    if (++dw == 3) { dw = 0; ++dh; }
  }

  // Epilogue. D layout: col = lane&15 (m), row = (lane>>4)*4 + reg (nout).
  const int colL = lane & 15, quad = lane >> 4;
#pragma unroll
  for (int fi = 0; fi < 4; ++fi) {
#pragma unroll
    for (int reg = 0; reg < 4; ++reg) {
      const int nout = n0 + wn + (fi << 4) + (quad << 2) + reg;
      const float bv = bias[nout];
      const int q = nout >> 8, co = nout & 255;
      const int ph = q & 1, pw = q >> 1;  // q: 0->(ev,ev) 1->(od,ev) 2->(ev,od) 3->(od,od)
#pragma unroll
      for (int fj = 0; fj < 4; ++fj) {
        const int mg = m0 + wm + (fj << 4) + colL;
        const int hh = (mg >> 5) & 31, ww = mg & 31;
        const int oidx = (((n_img << 8) + co) * 64 + (hh * 2 + ph)) * 64 +
                         (ww * 2 + pw);
        out[oidx] = acc[fi][fj][reg] + bv;
      }
    }
  }
}

// -------------------------------------------------------------- bn_stats ---
// One block per channel co: sum/sumsq over 16*64*64 = 65536 f32 values.
__global__ __launch_bounds__(256) void bn_stats(const float* __restrict__ y,
                                                float* __restrict__ stats) {
  const int co = blockIdx.x;
  const int t = threadIdx.x;
  float s = 0.f, s2 = 0.f;
  for (int n = 0; n < 16; ++n) {
    const float* p = y + (size_t)(n * 256 + co) * 4096;
#pragma unroll
    for (int it = 0; it < 4; ++it) {
      floatx4 v = *(const floatx4*)(p + (it * 256 + t) * 4);
#pragma unroll
      for (int e = 0; e < 4; ++e) {
        s += v[e];
        s2 += v[e] * v[e];
      }
    }
  }
#pragma unroll
  for (int off = 32; off > 0; off >>= 1) {
    s += __shfl_down(s, off);
    s2 += __shfl_down(s2, off);
  }
  __shared__ float red[8];
  const int wv = t >> 6, ln = t & 63;
  if (ln == 0) { red[wv] = s; red[4 + wv] = s2; }
  __syncthreads();
  if (t == 0) {
    const float S = red[0] + red[1] + red[2] + red[3];
    const float S2 = red[4] + red[5] + red[6] + red[7];
    const float mean = S * (1.f / 65536.f);
    const float var = S2 * (1.f / 65536.f) - mean * mean;
    stats[co] = mean;
    stats[256 + co] = rsqrtf(var + 1e-5f);
  }
}

// -------------------------------------------------------------- bn_apply ---
// In-place f32: y = relu((y - mean)*rstd*gamma + beta). Block per (n, co).
__global__ __launch_bounds__(256) void bn_apply(
    float* __restrict__ y, const float* __restrict__ stats,
    const float* __restrict__ gamma, const float* __restrict__ beta) {
  const int b = blockIdx.x;
  const int co = b & 255;
  const int t = threadIdx.x;
  const float mean = stats[co];
  const float rstd = stats[256 + co];
  const float scale = rstd * gamma[co];
  const float shift = beta[co] - mean * scale;
  float* p = y + (size_t)b * 4096;
#pragma unroll
  for (int it = 0; it < 4; ++it) {
    floatx4* q = (floatx4*)(p + (it * 256 + t) * 4);
    floatx4 v = *q;
#pragma unroll
    for (int e = 0; e < 4; ++e) v[e] = fmaxf(v[e] * scale + shift, 0.f);
    *q = v;
  }
}

// ---------------------------------------------------------------- launch ---
extern "C" void kernel_launch(void* const* d_in, const int* in_sizes, int n_in,
                              void* d_out, int out_size, void* d_ws,
                              size_t ws_size, hipStream_t stream) {
  const float* x  = (const float*)d_in[0];
  const float* w1 = (const float*)d_in[1];
  const float* b1 = (const float*)d_in[2];
  const float* w2 = (const float*)d_in[3];
  const float* b2 = (const float*)d_in[4];
  const float* w3 = (const float*)d_in[5];
  const float* b3 = (const float*)d_in[6];
  const float* w4 = (const float*)d_in[7];
  const float* b4 = (const float*)d_in[8];
  const float* gamma = (const float*)d_in[9];
  const float* beta  = (const float*)d_in[10];
  float* out = (float*)d_out;

  char* ws = (char*)d_ws;
  ushort_t* xt   = (ushort_t*)(ws + XT_OFF);
  ushort_t* wt   = (ushort_t*)(ws + WT_OFF);
  float*    bias = (float*)(ws + BIAS_OFF);
  float*    st   = (float*)(ws + STATS_OFF);

  prep_x<<<16 * 34, 256, 0, stream>>>(x, xt);
  prep_w<<<1024, 256, 0, stream>>>(w1, w2, w3, w4, b1, b2, b3, b4, wt, bias);
  gemm_kernel<<<1024, 256, 0, stream>>>(xt, wt, bias, out);
  bn_stats<<<256, 256, 0, stream>>>(out, st);
  bn_apply<<<4096, 256, 0, stream>>>(out, st, gamma, beta);
}